// Round 4
// baseline (75.596 us; speedup 1.0000x reference)
//
#include <hip/hip_runtime.h>

#define BB    16
#define NN    4096
#define DD    3
#define QPT   8                  // queries per thread (register tile)
#define TPB   256                // threads per block
#define QPB   (QPT * TPB)        // 2048 queries per block
#define QTILES (NN / QPB)        // 2
#define SPLIT 32                 // database split across blocks
#define SLICE (NN / SPLIT)       // 128 db points per block

__global__ __launch_bounds__(256) void chamfer_init_out(float* __restrict__ out) {
    int i = blockIdx.x * 256 + threadIdx.x;
    out[i] = 3.0e38f;
}

__global__ __launch_bounds__(TPB, 8) void chamfer_main(
    const float* __restrict__ xyz1,
    const float* __restrict__ xyz2,
    float* __restrict__ out) {
    // SoA db slice in LDS: x, y, z, h = x^2+y^2+z^2
    __shared__ __align__(16) float sx[SLICE];
    __shared__ __align__(16) float sy[SLICE];
    __shared__ __align__(16) float sz[SLICE];
    __shared__ __align__(16) float sh[SLICE];

    const int tid   = threadIdx.x;
    const int qtile = blockIdx.x;          // 0..QTILES-1
    const int b     = blockIdx.y;          // 0..B-1
    const int z     = blockIdx.z;          // 0..2*SPLIT-1
    const int dir   = z & 1;               // 0: dist1 (q=xyz1,db=xyz2), 1: dist2
    const int split = z >> 1;              // 0..SPLIT-1

    const float* qbase = (dir == 0 ? xyz1 : xyz2) + b * NN * DD;
    const float* dbase = (dir == 0 ? xyz2 : xyz1) + b * NN * DD;

    // ---- stage db slice into LDS (SoA), coalesced ----
    const float* g = dbase + split * SLICE * DD;
    for (int idx = tid; idx < SLICE * DD; idx += TPB) {
        float v = g[idx];
        int p = idx / 3;
        int c = idx - 3 * p;
        (c == 0 ? sx : (c == 1 ? sy : sz))[p] = v;
    }
    __syncthreads();
    // ---- compute h per db point ----
    if (tid < SLICE) {
        float x = sx[tid], y = sy[tid], zz = sz[tid];
        sh[tid] = fmaf(x, x, fmaf(y, y, zz * zz));
    }

    // ---- load my 8 query points; precompute a = -2q, s1 = ||q||^2 ----
    const int q0 = qtile * QPB + tid;
    float ax[QPT], ay[QPT], az[QPT], s1[QPT], bA[QPT];
#pragma unroll
    for (int i = 0; i < QPT; ++i) {
        const float* p = qbase + (q0 + i * TPB) * DD;
        float x = p[0], y = p[1], zz = p[2];
        ax[i] = -2.0f * x;
        ay[i] = -2.0f * y;
        az[i] = -2.0f * zz;
        s1[i] = fmaf(x, x, fmaf(y, y, zz * zz));
        bA[i] = 3.0e38f;
    }
    __syncthreads();

    // ---- sweep db slice, 8 points/iter via broadcast b128 reads ----
    for (int j = 0; j < SLICE; j += 8) {
        float4 X[2], Y[2], Z[2], H[2];
#pragma unroll
        for (int u = 0; u < 2; ++u) {
            X[u] = *(const float4*)&sx[j + 4 * u];
            Y[u] = *(const float4*)&sy[j + 4 * u];
            Z[u] = *(const float4*)&sz[j + 4 * u];
            H[u] = *(const float4*)&sh[j + 4 * u];
        }
#pragma unroll
        for (int u = 0; u < 2; ++u) {
#pragma unroll
            for (int i = 0; i < QPT; ++i) {
                float t0 = fmaf(ax[i], X[u].x, fmaf(ay[i], Y[u].x, fmaf(az[i], Z[u].x, H[u].x)));
                float t1 = fmaf(ax[i], X[u].y, fmaf(ay[i], Y[u].y, fmaf(az[i], Z[u].y, H[u].y)));
                float t2 = fmaf(ax[i], X[u].z, fmaf(ay[i], Y[u].z, fmaf(az[i], Z[u].z, H[u].z)));
                float t3 = fmaf(ax[i], X[u].w, fmaf(ay[i], Y[u].w, fmaf(az[i], Z[u].w, H[u].w)));
                bA[i] = fminf(fminf(t0, t1), bA[i]);   // v_min3_f32 candidate
                bA[i] = fminf(fminf(t2, t3), bA[i]);
            }
        }
    }

    // ---- combine partials across M-splits via int atomicMin (d2 >= 0) ----
    const int obase = dir * (BB * NN) + b * NN + q0;
#pragma unroll
    for (int i = 0; i < QPT; ++i) {
        float best = fmaxf(s1[i] + bA[i], 0.0f);
        atomicMin((int*)out + obase + i * TPB, __float_as_int(best));
    }
}

extern "C" void kernel_launch(void* const* d_in, const int* in_sizes, int n_in,
                              void* d_out, int out_size, void* d_ws, size_t ws_size,
                              hipStream_t stream) {
    const float* xyz1 = (const float*)d_in[0];
    const float* xyz2 = (const float*)d_in[1];
    float* out = (float*)d_out;

    // init output to +big (harness poisons d_out; must rewrite every call)
    hipLaunchKernelGGL(chamfer_init_out, dim3(2 * BB * NN / 256), dim3(256), 0, stream, out);

    dim3 grid(QTILES, BB, 2 * SPLIT);
    hipLaunchKernelGGL(chamfer_main, grid, dim3(TPB), 0, stream, xyz1, xyz2, out);
}

// Round 5
// 48.796 us; speedup vs baseline: 1.5492x; 1.5492x over previous
//
#include <hip/hip_runtime.h>

#define BB    16
#define NN    4096
#define DD    3
#define QPT   8                  // queries per thread (register tile)
#define TPB   256                // threads per block
#define QPB   (QPT * TPB)        // 2048 queries per block
#define QTILES (NN / QPB)        // 2
#define SPLIT 32                 // database split across blocks
#define SLICE (NN / SPLIT)       // 128 db points per block

__global__ __launch_bounds__(256) void chamfer_init_out(float* __restrict__ out) {
    int i = blockIdx.x * 256 + threadIdx.x;
    out[i] = 3.0e38f;
}

// NOTE: no min-waves arg — R4 showed __launch_bounds__(256,8) caps VGPR at 32
// and spills the register tile (FETCH 0.8->50MB, WRITE 16->123MB). At ~52 VGPR
// the allocator naturally fits 8 waves/SIMD.
__global__ __launch_bounds__(TPB) void chamfer_main(
    const float* __restrict__ xyz1,
    const float* __restrict__ xyz2,
    float* __restrict__ out) {
    // SoA db slice in LDS: x, y, z, h = x^2+y^2+z^2
    __shared__ __align__(16) float sx[SLICE];
    __shared__ __align__(16) float sy[SLICE];
    __shared__ __align__(16) float sz[SLICE];
    __shared__ __align__(16) float sh[SLICE];

    const int tid   = threadIdx.x;
    const int qtile = blockIdx.x;          // 0..QTILES-1
    const int b     = blockIdx.y;          // 0..B-1
    const int z     = blockIdx.z;          // 0..2*SPLIT-1
    const int dir   = z & 1;               // 0: dist1 (q=xyz1,db=xyz2), 1: dist2
    const int split = z >> 1;              // 0..SPLIT-1

    const float* qbase = (dir == 0 ? xyz1 : xyz2) + b * NN * DD;
    const float* dbase = (dir == 0 ? xyz2 : xyz1) + b * NN * DD;

    // ---- stage db slice into LDS (SoA), coalesced ----
    const float* g = dbase + split * SLICE * DD;
    for (int idx = tid; idx < SLICE * DD; idx += TPB) {
        float v = g[idx];
        int p = idx / 3;
        int c = idx - 3 * p;
        (c == 0 ? sx : (c == 1 ? sy : sz))[p] = v;
    }
    __syncthreads();
    // ---- compute h per db point ----
    if (tid < SLICE) {
        float x = sx[tid], y = sy[tid], zz = sz[tid];
        sh[tid] = fmaf(x, x, fmaf(y, y, zz * zz));
    }

    // ---- load my 8 query points; precompute a = -2q, s1 = ||q||^2 ----
    const int q0 = qtile * QPB + tid;
    float ax[QPT], ay[QPT], az[QPT], s1[QPT], bA[QPT];
#pragma unroll
    for (int i = 0; i < QPT; ++i) {
        const float* p = qbase + (q0 + i * TPB) * DD;
        float x = p[0], y = p[1], zz = p[2];
        ax[i] = -2.0f * x;
        ay[i] = -2.0f * y;
        az[i] = -2.0f * zz;
        s1[i] = fmaf(x, x, fmaf(y, y, zz * zz));
        bA[i] = 3.0e38f;
    }
    __syncthreads();

    // ---- sweep db slice, 8 points/iter via broadcast b128 reads ----
    for (int j = 0; j < SLICE; j += 8) {
        float4 X[2], Y[2], Z[2], H[2];
#pragma unroll
        for (int u = 0; u < 2; ++u) {
            X[u] = *(const float4*)&sx[j + 4 * u];
            Y[u] = *(const float4*)&sy[j + 4 * u];
            Z[u] = *(const float4*)&sz[j + 4 * u];
            H[u] = *(const float4*)&sh[j + 4 * u];
        }
#pragma unroll
        for (int u = 0; u < 2; ++u) {
#pragma unroll
            for (int i = 0; i < QPT; ++i) {
                float t0 = fmaf(ax[i], X[u].x, fmaf(ay[i], Y[u].x, fmaf(az[i], Z[u].x, H[u].x)));
                float t1 = fmaf(ax[i], X[u].y, fmaf(ay[i], Y[u].y, fmaf(az[i], Z[u].y, H[u].y)));
                float t2 = fmaf(ax[i], X[u].z, fmaf(ay[i], Y[u].z, fmaf(az[i], Z[u].z, H[u].z)));
                float t3 = fmaf(ax[i], X[u].w, fmaf(ay[i], Y[u].w, fmaf(az[i], Z[u].w, H[u].w)));
                bA[i] = fminf(fminf(t0, t1), bA[i]);   // v_min3_f32 candidate
                bA[i] = fminf(fminf(t2, t3), bA[i]);
            }
        }
    }

    // ---- combine partials across M-splits via int atomicMin (d2 >= 0) ----
    const int obase = dir * (BB * NN) + b * NN + q0;
#pragma unroll
    for (int i = 0; i < QPT; ++i) {
        float best = fmaxf(s1[i] + bA[i], 0.0f);
        atomicMin((int*)out + obase + i * TPB, __float_as_int(best));
    }
}

extern "C" void kernel_launch(void* const* d_in, const int* in_sizes, int n_in,
                              void* d_out, int out_size, void* d_ws, size_t ws_size,
                              hipStream_t stream) {
    const float* xyz1 = (const float*)d_in[0];
    const float* xyz2 = (const float*)d_in[1];
    float* out = (float*)d_out;

    // init output to +big (harness poisons d_out; must rewrite every call)
    hipLaunchKernelGGL(chamfer_init_out, dim3(2 * BB * NN / 256), dim3(256), 0, stream, out);

    dim3 grid(QTILES, BB, 2 * SPLIT);
    hipLaunchKernelGGL(chamfer_main, grid, dim3(TPB), 0, stream, xyz1, xyz2, out);
}